// Round 9
// baseline (592.534 us; speedup 1.0000x reference)
//
#include <hip/hip_runtime.h>

#define HD 128
#define RNUM 8
#define SCAN_BS 2048

typedef __attribute__((ext_vector_type(8))) short short8;
typedef __attribute__((ext_vector_type(4))) float float4e;

__device__ __forceinline__ unsigned short f2bf(float f) {
    unsigned int u = __float_as_uint(f);
    u += 0x7fffu + ((u >> 16) & 1u);   // RNE
    return (unsigned short)(u >> 16);
}

__device__ __forceinline__ unsigned int pk2(float lo, float hi) {
    return (unsigned int)f2bf(lo) | ((unsigned int)f2bf(hi) << 16);
}

// accumulate 2 bf16 packed in u into a[i], a[i+1]
__device__ __forceinline__ void acc2(float4e& a, unsigned int u, int i) {
    a[i]     += __uint_as_float(u << 16);
    a[i + 1] += __uint_as_float(u & 0xffff0000u);
}

__device__ __forceinline__ void gload_lds16(const void* g, void* l) {
    __builtin_amdgcn_global_load_lds(
        (const __attribute__((address_space(1))) void*)g,
        (__attribute__((address_space(3))) void*)l, 16, 0, 0);
}

// ---------------- small kernels ----------------
__global__ void zero_i(int* __restrict__ p, int n) {
    int g = blockIdx.x * blockDim.x + threadIdx.x;
    if (g < n) p[g] = 0;
}

// weights -> bf16 transposed WT[mat][f][d], plus emb -> bf16, one launch
__global__ void prep_kernel(const float* __restrict__ W1, const float* __restrict__ r1,
                            const float* __restrict__ W2, const float* __restrict__ r2,
                            unsigned short* __restrict__ WT,
                            const float* __restrict__ emb, unsigned short* __restrict__ emb16,
                            long long n8) {
    long long g = (long long)blockIdx.x * blockDim.x + threadIdx.x;
    if (g < 18 * 16384) {
        int gi = (int)g;
        int mat = gi >> 14;
        int idx = gi & 16383;
        int d = idx >> 7;
        int f = idx & 127;
        const float* src;
        int m;
        if (mat < 8)       { src = W1; m = mat; }
        else if (mat == 8) { src = r1; m = 0; }
        else if (mat < 17) { src = W2; m = mat - 9; }
        else               { src = r2; m = 0; }
        WT[mat * 16384 + f * 128 + d] = f2bf(src[(size_t)m * 16384 + d * 128 + f]);
    }
    long long h = g - 18 * 16384;
    if (h >= 0 && h < n8) {
        const float4* p = (const float4*)(emb + h * 8);
        float4 v0 = p[0], v1 = p[1];
        uint4 o;
        o.x = pk2(v0.x, v0.y);
        o.y = pk2(v0.z, v0.w);
        o.z = pk2(v1.x, v1.y);
        o.w = pk2(v1.z, v1.w);
        *(uint4*)(emb16 + h * 8) = o;
    }
}

// ---------------- CSR build (dst-major: seg = dst*8 + r) ----------------
__global__ void count_kernel(const int* __restrict__ ei, const int* __restrict__ et,
                             int* __restrict__ cnt, int E, int N) {
    int e = blockIdx.x * blockDim.x + threadIdx.x;
    if (e < E) atomicAdd(&cnt[ei[E + e] * RNUM + et[e]], 1);
}

__global__ void scan1(const int* __restrict__ in, int* __restrict__ out,
                      int* __restrict__ bsum, int n) {
    __shared__ int s[256];
    const int tid = threadIdx.x;
    const int base = blockIdx.x * SCAN_BS + tid * 8;
    int v[8];
    int sum = 0;
#pragma unroll
    for (int j = 0; j < 8; j++) {
        int x = (base + j < n) ? in[base + j] : 0;
        v[j] = sum;
        sum += x;
    }
    s[tid] = sum;
    __syncthreads();
    for (int off = 1; off < 256; off <<= 1) {
        int tv = (tid >= off) ? s[tid - off] : 0;
        __syncthreads();
        if (tid >= off) s[tid] += tv;
        __syncthreads();
    }
    int excl = (tid > 0) ? s[tid - 1] : 0;
    if (tid == 255) bsum[blockIdx.x] = s[255];
#pragma unroll
    for (int j = 0; j < 8; j++)
        if (base + j < n) out[base + j] = v[j] + excl;
}

__global__ void scan2(int* __restrict__ bsum, int nb) {
    __shared__ int s[512];
    const int tid = threadIdx.x;
    s[tid] = (tid < nb) ? bsum[tid] : 0;
    __syncthreads();
    for (int off = 1; off < 512; off <<= 1) {
        int tv = (tid >= off) ? s[tid - off] : 0;
        __syncthreads();
        if (tid >= off) s[tid] += tv;
        __syncthreads();
    }
    if (tid < nb) bsum[tid] = (tid > 0) ? s[tid - 1] : 0;
}

__global__ void scan3(int* __restrict__ out, int* __restrict__ cur,
                      const int* __restrict__ bsum, int n) {
    const int base = blockIdx.x * SCAN_BS + threadIdx.x * 8;
    const int add = bsum[blockIdx.x];
#pragma unroll
    for (int j = 0; j < 8; j++) {
        int i = base + j;
        if (i < n) {
            int v = out[i] + add;
            out[i] = v;
            cur[i] = v;
        }
    }
}

// fill: col = src node id (layer 2), colE = pre-resolved entity id (layer 1).
// Thread 0 also writes the terminating boundary row_start[8*N] = E.
__global__ void fill_kernel(const int* __restrict__ ei, const int* __restrict__ et,
                            const int* __restrict__ ids,
                            int* __restrict__ cur, int* __restrict__ col,
                            int* __restrict__ colE, int* __restrict__ row_start,
                            int E, int N) {
    int e = blockIdx.x * blockDim.x + threadIdx.x;
    if (e == 0) row_start[RNUM * N] = E;
    if (e < E) {
        int src = ei[e];
        int pos = atomicAdd(&cur[ei[E + e] * RNUM + et[e]], 1);
        col[pos] = src;
        colE[pos] = ids[src];
    }
}

// ---------------- fused layer ----------------
// 256 threads = 4 waves, 64-row tile. LDS = As 16 KB + Ws 32 KB -> 3 blocks/CU.
// dst-major CSR: row's 9 boundaries in ONE cache line; edge span contiguous.
// Walk uses 4-deep memory-level parallelism: issue 4 edges' loads before
// accumulating, so the barrier-max outlier rows pay ~1 latency instead of 4-5.
template <bool HAS_IDX, int ACT>   // ACT: 0 = relu -> bf16 out, 1 = sigmoid -> f32 out
__launch_bounds__(256, 3)
__global__ void rgcn_fused(const int* __restrict__ row_start, const int* __restrict__ col,
                           const int* __restrict__ ids,
                           const unsigned short* __restrict__ x16,
                           const unsigned short* __restrict__ WT,
                           const float* __restrict__ bias,
                           void* __restrict__ CoutV, int N, int E) {
    __shared__ unsigned short As[64 * 128];    // 16 KB
    __shared__ unsigned short Ws[128 * 128];   // 32 KB

    const int tid = threadIdx.x;
    const int block0 = blockIdx.x * 64;
    // MFMA mapping (4 waves: 2 row strips of 32 x 2 col strips of 64)
    const int w = tid >> 6;
    const int lane = tid & 63;
    const int ln15 = lane & 15;
    const int quad = lane >> 4;
    const int rowbase = (w & 1) * 32;
    const int colbase = (w >> 1) * 64;
    // agg mapping: 64 groups of 4 lanes; group g owns row g (64 B per lane)
    const int grp = tid >> 2;
    const int sub4 = tid & 3;
    const int mydst = block0 + grp;
    const bool rowok = (mydst < N);

    float4e acc[2][4];
#pragma unroll
    for (int i = 0; i < 2; i++)
#pragma unroll
        for (int j = 0; j < 4; j++)
#pragma unroll
            for (int q = 0; q < 4; q++) acc[i][j][q] = 0.0f;

#pragma unroll 1
    for (int s = 0; s < RNUM; s++) {
        // ---- stage Ws(s): async DMA; latency hides under the walk below ----
        {
            const unsigned short* Wsrc = WT + s * 16384;
#pragma unroll
            for (int i = 0; i < 8; i++) {
                int c = i * 256 + tid;
                int f = c >> 4;
                int cc = c & 15;
                const void* src = (const void*)(Wsrc + f * 128 + ((cc ^ (f & 15)) << 3));
                int cbase = i * 256 + (tid & ~63);   // wave-uniform base, +lane*16
                gload_lds16(src, (char*)Ws + (size_t)cbase * 16);
            }
        }
        // ---- stage A tile: mean-aggregate with 4-deep MLP walk ----
        {
            float4e a[8];
#pragma unroll
            for (int j = 0; j < 8; j++) a[j] = (float4e){0.f, 0.f, 0.f, 0.f};
            int s0 = 0, s1 = 0;
            if (rowok) {
                s0 = row_start[mydst * 8 + s];
                s1 = row_start[mydst * 8 + s + 1];
            }
            const float inv = (s1 > s0) ? 1.0f / (float)(s1 - s0) : 0.0f;
#pragma unroll 1
            for (int base = s0; base < s1; base += 4) {
                const int m = s1 - base;     // remaining edges (>=1 inside loop)
                int cc[4];
                uint4 v0[4], v1[4], v2[4], v3[4];
#pragma unroll
                for (int j = 0; j < 4; j++)
                    if (j < m) cc[j] = col[base + j];
#pragma unroll
                for (int j = 0; j < 4; j++)
                    if (j < m) {
                        const uint4* xp = (const uint4*)(x16 + (size_t)cc[j] * HD + sub4 * 32);
                        v0[j] = xp[0]; v1[j] = xp[1]; v2[j] = xp[2]; v3[j] = xp[3];
                    }
#pragma unroll
                for (int j = 0; j < 4; j++)
                    if (j < m) {
                        acc2(a[0], v0[j].x, 0); acc2(a[0], v0[j].y, 2);
                        acc2(a[1], v0[j].z, 0); acc2(a[1], v0[j].w, 2);
                        acc2(a[2], v1[j].x, 0); acc2(a[2], v1[j].y, 2);
                        acc2(a[3], v1[j].z, 0); acc2(a[3], v1[j].w, 2);
                        acc2(a[4], v2[j].x, 0); acc2(a[4], v2[j].y, 2);
                        acc2(a[5], v2[j].z, 0); acc2(a[5], v2[j].w, 2);
                        acc2(a[6], v3[j].x, 0); acc2(a[6], v3[j].y, 2);
                        acc2(a[7], v3[j].z, 0); acc2(a[7], v3[j].w, 2);
                    }
            }
#pragma unroll
            for (int j = 0; j < 8; j++) a[j] *= inv;
#pragma unroll
            for (int j = 0; j < 4; j++) {
                uint4 o;
                o.x = pk2(a[2 * j][0], a[2 * j][1]);
                o.y = pk2(a[2 * j][2], a[2 * j][3]);
                o.z = pk2(a[2 * j + 1][0], a[2 * j + 1][1]);
                o.w = pk2(a[2 * j + 1][2], a[2 * j + 1][3]);
                int ck = sub4 * 4 + j;
                *(uint4*)&As[grp * 128 + ((ck ^ (grp & 15)) << 3)] = o;
            }
        }
        __syncthreads();

        // ---- MFMA: A and B from LDS ----
#pragma unroll
        for (int k0 = 0; k0 < 4; k0++) {
            short8 af[2], bf[4];
            const int ck = k0 * 4 + quad;
#pragma unroll
            for (int rt = 0; rt < 2; rt++) {
                int m = rowbase + rt * 16 + ln15;
                af[rt] = *(const short8*)&As[m * 128 + ((ck ^ (m & 15)) << 3)];
            }
#pragma unroll
            for (int ct = 0; ct < 4; ct++) {
                int n = colbase + ct * 16 + ln15;
                bf[ct] = *(const short8*)&Ws[n * 128 + ((ck ^ (n & 15)) << 3)];
            }
#pragma unroll
            for (int rt = 0; rt < 2; rt++)
#pragma unroll
                for (int ct = 0; ct < 4; ct++)
                    acc[rt][ct] = __builtin_amdgcn_mfma_f32_16x16x32_bf16(
                        af[rt], bf[ct], acc[rt][ct], 0, 0, 0);
        }
        __syncthreads();
    }

    // ---- root/self phase (s == 8) ----
    {
        const unsigned short* Wsrc = WT + RNUM * 16384;
#pragma unroll
        for (int i = 0; i < 8; i++) {
            int c = i * 256 + tid;
            int f = c >> 4;
            int cc = c & 15;
            const void* src = (const void*)(Wsrc + f * 128 + ((cc ^ (f & 15)) << 3));
            int cbase = i * 256 + (tid & ~63);
            gload_lds16(src, (char*)Ws + (size_t)cbase * 16);
        }
        uint4 o0 = {0u, 0u, 0u, 0u}, o1 = o0, o2 = o0, o3 = o0;
        if (rowok) {
            int srcn = HAS_IDX ? ids[mydst] : mydst;
            const uint4* xp = (const uint4*)(x16 + (size_t)srcn * HD + sub4 * 32);
            o0 = xp[0]; o1 = xp[1]; o2 = xp[2]; o3 = xp[3];
        }
        const int ck0 = sub4 * 4;
        *(uint4*)&As[grp * 128 + (((ck0 + 0) ^ (grp & 15)) << 3)] = o0;
        *(uint4*)&As[grp * 128 + (((ck0 + 1) ^ (grp & 15)) << 3)] = o1;
        *(uint4*)&As[grp * 128 + (((ck0 + 2) ^ (grp & 15)) << 3)] = o2;
        *(uint4*)&As[grp * 128 + (((ck0 + 3) ^ (grp & 15)) << 3)] = o3;
        __syncthreads();
#pragma unroll
        for (int k0 = 0; k0 < 4; k0++) {
            short8 af[2], bf[4];
            const int ck = k0 * 4 + quad;
#pragma unroll
            for (int rt = 0; rt < 2; rt++) {
                int m = rowbase + rt * 16 + ln15;
                af[rt] = *(const short8*)&As[m * 128 + ((ck ^ (m & 15)) << 3)];
            }
#pragma unroll
            for (int ct = 0; ct < 4; ct++) {
                int n = colbase + ct * 16 + ln15;
                bf[ct] = *(const short8*)&Ws[n * 128 + ((ck ^ (n & 15)) << 3)];
            }
#pragma unroll
            for (int rt = 0; rt < 2; rt++)
#pragma unroll
                for (int ct = 0; ct < 4; ct++)
                    acc[rt][ct] = __builtin_amdgcn_mfma_f32_16x16x32_bf16(
                        af[rt], bf[ct], acc[rt][ct], 0, 0, 0);
        }
        __syncthreads();
    }

    // ---- epilogue ----
#pragma unroll
    for (int ct = 0; ct < 4; ct++) {
        int ncol = colbase + ct * 16 + ln15;
        float bv = bias[ncol];
#pragma unroll
        for (int rt = 0; rt < 2; rt++) {
#pragma unroll
            for (int rg = 0; rg < 4; rg++) {
                int rowg = block0 + rowbase + rt * 16 + quad * 4 + rg;
                if (rowg < N) {
                    float v = acc[rt][ct][rg] + bv;
                    if (ACT == 0) {
                        v = fmaxf(v, 0.0f);
                        ((unsigned short*)CoutV)[(size_t)rowg * HD + ncol] = f2bf(v);
                    } else {
                        v = 1.0f / (1.0f + expf(-v));
                        ((float*)CoutV)[(size_t)rowg * HD + ncol] = v;
                    }
                }
            }
        }
    }
}

extern "C" void kernel_launch(void* const* d_in, const int* in_sizes, int n_in,
                              void* d_out, int out_size, void* d_ws, size_t ws_size,
                              hipStream_t stream) {
    const int*   x_ids = (const int*)d_in[0];
    const int*   ei    = (const int*)d_in[1];
    const int*   et    = (const int*)d_in[2];
    const float* emb   = (const float*)d_in[3];
    const float* W1    = (const float*)d_in[4];
    const float* root1 = (const float*)d_in[5];
    const float* b1    = (const float*)d_in[6];
    const float* W2    = (const float*)d_in[7];
    const float* root2 = (const float*)d_in[8];
    const float* b2    = (const float*)d_in[9];

    const int N = in_sizes[0];
    const int E = in_sizes[1] / 2;
    const int NS = RNUM * N;
    const long long embElems = (long long)in_sizes[3];   // NUM_ENTITIES * HD
    float* out = (float*)d_out;

    // ---- arenas (row_start has NS+1 entries, padded to 16 B) ----
    char* ws = (char*)d_ws;
    size_t off = 0;
    int* row_start = (int*)(ws + off); off += (size_t)(NS + 4) * 4;             // 3.2 MB
    int* col       = (int*)(ws + off); off += (size_t)E * 4;                    // 2.0 MB
    int* colE      = (int*)(ws + off); off += (size_t)E * 4;                    // 2.0 MB
    int* bsum      = (int*)(ws + off); off += 4096;
    unsigned short* WT    = (unsigned short*)(ws + off); off += (size_t)18 * 16384 * 2;
    unsigned short* emb16 = (unsigned short*)(ws + off); off += (size_t)embElems * 2;  // 25.6 MB
    unsigned short* z16   = (unsigned short*)(ws + off); off += (size_t)N * HD * 2;    // 25.6 MB
    int* cur = (int*)z16;   // alias: cur dead before z16 is first written

    const int scanBlocks = (NS + SCAN_BS - 1) / SCAN_BS;
    const int layerGrid = (N + 63) / 64;

    // ---- CSR build (dst-major) ----
    zero_i<<<(NS + 255) / 256, 256, 0, stream>>>(cur, NS);
    count_kernel<<<(E + 255) / 256, 256, 0, stream>>>(ei, et, cur, E, N);
    scan1<<<scanBlocks, 256, 0, stream>>>(cur, row_start, bsum, NS);
    scan2<<<1, 512, 0, stream>>>(bsum, scanBlocks);
    scan3<<<scanBlocks, 256, 0, stream>>>(row_start, cur, bsum, NS);
    fill_kernel<<<(E + 255) / 256, 256, 0, stream>>>(ei, et, x_ids, cur, col, colE,
                                                     row_start, E, N);

    // ---- weights -> bf16 transposed + emb -> bf16 (one launch) ----
    {
        long long n8 = embElems / 8;
        long long total = 18 * 16384 + n8;
        prep_kernel<<<(unsigned int)((total + 255) / 256), 256, 0, stream>>>(
            W1, root1, W2, root2, WT, emb, emb16, n8);
    }

    // ---- layer 1: z16 = bf16(relu(agg(emb16) + emb16[ids]@root1 + b1)) ----
    rgcn_fused<true, 0><<<layerGrid, 256, 0, stream>>>(
        row_start, colE, x_ids, emb16, WT, b1, (void*)z16, N, E);
    // ---- layer 2: out = sigmoid(agg(z16) + z16@root2 + b2) ----
    rgcn_fused<false, 1><<<layerGrid, 256, 0, stream>>>(
        row_start, col, nullptr, z16, WT + 9 * 16384, b2, (void*)out, N, E);
}

// Round 10
// 504.829 us; speedup vs baseline: 1.1737x; 1.1737x over previous
//
#include <hip/hip_runtime.h>

#define HD 128
#define RNUM 8
#define SCAN_BS 2048

typedef __attribute__((ext_vector_type(8))) short short8;
typedef __attribute__((ext_vector_type(4))) float float4e;

__device__ __forceinline__ unsigned short f2bf(float f) {
    unsigned int u = __float_as_uint(f);
    u += 0x7fffu + ((u >> 16) & 1u);   // RNE
    return (unsigned short)(u >> 16);
}

__device__ __forceinline__ unsigned int pk2(float lo, float hi) {
    return (unsigned int)f2bf(lo) | ((unsigned int)f2bf(hi) << 16);
}

// accumulate 2 bf16 packed in u into a[i], a[i+1]
__device__ __forceinline__ void acc2(float4e& a, unsigned int u, int i) {
    a[i]     += __uint_as_float(u << 16);
    a[i + 1] += __uint_as_float(u & 0xffff0000u);
}

__device__ __forceinline__ void gload_lds16(const void* g, void* l) {
    __builtin_amdgcn_global_load_lds(
        (const __attribute__((address_space(1))) void*)g,
        (__attribute__((address_space(3))) void*)l, 16, 0, 0);
}

// ---------------- small kernels ----------------
__global__ void zero_i(int* __restrict__ p, int n) {
    int g = blockIdx.x * blockDim.x + threadIdx.x;
    if (g < n) p[g] = 0;
}

// weights -> bf16 transposed WT[mat][f][d], plus emb -> bf16, one launch
__global__ void prep_kernel(const float* __restrict__ W1, const float* __restrict__ r1,
                            const float* __restrict__ W2, const float* __restrict__ r2,
                            unsigned short* __restrict__ WT,
                            const float* __restrict__ emb, unsigned short* __restrict__ emb16,
                            long long n8) {
    long long g = (long long)blockIdx.x * blockDim.x + threadIdx.x;
    if (g < 18 * 16384) {
        int gi = (int)g;
        int mat = gi >> 14;
        int idx = gi & 16383;
        int d = idx >> 7;
        int f = idx & 127;
        const float* src;
        int m;
        if (mat < 8)       { src = W1; m = mat; }
        else if (mat == 8) { src = r1; m = 0; }
        else if (mat < 17) { src = W2; m = mat - 9; }
        else               { src = r2; m = 0; }
        WT[mat * 16384 + f * 128 + d] = f2bf(src[(size_t)m * 16384 + d * 128 + f]);
    }
    long long h = g - 18 * 16384;
    if (h >= 0 && h < n8) {
        const float4* p = (const float4*)(emb + h * 8);
        float4 v0 = p[0], v1 = p[1];
        uint4 o;
        o.x = pk2(v0.x, v0.y);
        o.y = pk2(v0.z, v0.w);
        o.z = pk2(v1.x, v1.y);
        o.w = pk2(v1.z, v1.w);
        *(uint4*)(emb16 + h * 8) = o;
    }
}

// ---------------- CSR build (dst-major: seg = dst*8 + r) ----------------
__global__ void count_kernel(const int* __restrict__ ei, const int* __restrict__ et,
                             int* __restrict__ cnt, int E, int N) {
    int e = blockIdx.x * blockDim.x + threadIdx.x;
    if (e < E) atomicAdd(&cnt[ei[E + e] * RNUM + et[e]], 1);
}

__global__ void scan1(const int* __restrict__ in, int* __restrict__ out,
                      int* __restrict__ bsum, int n) {
    __shared__ int s[256];
    const int tid = threadIdx.x;
    const int base = blockIdx.x * SCAN_BS + tid * 8;
    int v[8];
    int sum = 0;
#pragma unroll
    for (int j = 0; j < 8; j++) {
        int x = (base + j < n) ? in[base + j] : 0;
        v[j] = sum;
        sum += x;
    }
    s[tid] = sum;
    __syncthreads();
    for (int off = 1; off < 256; off <<= 1) {
        int tv = (tid >= off) ? s[tid - off] : 0;
        __syncthreads();
        if (tid >= off) s[tid] += tv;
        __syncthreads();
    }
    int excl = (tid > 0) ? s[tid - 1] : 0;
    if (tid == 255) bsum[blockIdx.x] = s[255];
#pragma unroll
    for (int j = 0; j < 8; j++)
        if (base + j < n) out[base + j] = v[j] + excl;
}

__global__ void scan2(int* __restrict__ bsum, int nb) {
    __shared__ int s[512];
    const int tid = threadIdx.x;
    s[tid] = (tid < nb) ? bsum[tid] : 0;
    __syncthreads();
    for (int off = 1; off < 512; off <<= 1) {
        int tv = (tid >= off) ? s[tid - off] : 0;
        __syncthreads();
        if (tid >= off) s[tid] += tv;
        __syncthreads();
    }
    if (tid < nb) bsum[tid] = (tid > 0) ? s[tid - 1] : 0;
}

__global__ void scan3(int* __restrict__ out, int* __restrict__ cur,
                      const int* __restrict__ bsum, int n) {
    const int base = blockIdx.x * SCAN_BS + threadIdx.x * 8;
    const int add = bsum[blockIdx.x];
#pragma unroll
    for (int j = 0; j < 8; j++) {
        int i = base + j;
        if (i < n) {
            int v = out[i] + add;
            out[i] = v;
            cur[i] = v;
        }
    }
}

// fill: col = src node id (layer 2), colE = pre-resolved entity id (layer 1).
// Thread 0 also writes the terminating boundary row_start[8*N] = E.
__global__ void fill_kernel(const int* __restrict__ ei, const int* __restrict__ et,
                            const int* __restrict__ ids,
                            int* __restrict__ cur, int* __restrict__ col,
                            int* __restrict__ colE, int* __restrict__ row_start,
                            int E, int N) {
    int e = blockIdx.x * blockDim.x + threadIdx.x;
    if (e == 0) row_start[RNUM * N] = E;
    if (e < E) {
        int src = ei[e];
        int pos = atomicAdd(&cur[ei[E + e] * RNUM + et[e]], 1);
        col[pos] = src;
        colE[pos] = ids[src];
    }
}

// ---------------- fused layer: register-walk, single walk-max amortization ----------------
// 512 threads = 8 waves, 64-row tile. As 16 KB + Ws 32 KB -> 2 blocks/CU.
// Phase structure: walk ALL 8 relations first into registers p[8][2] (one 8-lane
// group per row, segments contiguous in dst-major CSR; walk-max paid ONCE),
// then 9 uniform phases {ds_write p[s] -> barrier -> MFMA -> barrier -> DMA Ws(s+1)}
// whose barriers bound only uniform-latency work.
template <bool HAS_IDX, int ACT>   // ACT: 0 = relu -> bf16 out, 1 = sigmoid -> f32 out
__launch_bounds__(512, 4)
__global__ void rgcn_fused(const int* __restrict__ row_start, const int* __restrict__ col,
                           const int* __restrict__ ids,
                           const unsigned short* __restrict__ x16,
                           const unsigned short* __restrict__ WT,
                           const float* __restrict__ bias,
                           void* __restrict__ CoutV, int N, int E) {
    __shared__ unsigned short As[64 * 128];    // 16 KB
    __shared__ unsigned short Ws[128 * 128];   // 32 KB

    const int tid = threadIdx.x;
    const int block0 = blockIdx.x * 64;
    // MFMA mapping (8 waves: 2 row strips of 32 x 4 col strips of 32)
    const int w = tid >> 6;
    const int lane = tid & 63;
    const int ln15 = lane & 15;
    const int quad = lane >> 4;
    const int rowbase = (w & 1) * 32;
    const int colbase = (w >> 1) * 32;
    // walk mapping: 64 groups of 8 lanes; group g owns row g (32 B per lane)
    const int grp = tid >> 3;
    const int sub8 = tid & 7;
    const int mydst = block0 + grp;
    const bool rowok = (mydst < N);

    // ---- stage Ws(0): async DMA, in flight across the walk ----
    {
        const unsigned short* Wsrc = WT;
#pragma unroll
        for (int i = 0; i < 4; i++) {
            int c = i * 512 + tid;
            int f = c >> 4;
            int cc = c & 15;
            const void* src = (const void*)(Wsrc + f * 128 + ((cc ^ (f & 15)) << 3));
            int cbase = i * 512 + (tid & ~63);   // wave-uniform base, +lane*16
            gload_lds16(src, (char*)Ws + (size_t)cbase * 16);
        }
    }

    // ---- walk all 8 relations (serial per group; contiguous col span per row) ----
    uint4 p[8][2];
#pragma unroll
    for (int r = 0; r < 8; r++) {
        float4e a0 = {0.f, 0.f, 0.f, 0.f};
        float4e a1 = {0.f, 0.f, 0.f, 0.f};
        float4e a2 = {0.f, 0.f, 0.f, 0.f};
        float4e a3 = {0.f, 0.f, 0.f, 0.f};
        int s0 = 0, s1 = 0;
        if (rowok) {
            s0 = row_start[mydst * 8 + r];
            s1 = row_start[mydst * 8 + r + 1];
        }
#pragma unroll 1
        for (int e = s0; e < s1; e++) {
            int c = col[e];
            const uint4* xp = (const uint4*)(x16 + (size_t)c * HD + sub8 * 16);
            uint4 v0 = xp[0], v1 = xp[1];
            acc2(a0, v0.x, 0); acc2(a0, v0.y, 2);
            acc2(a1, v0.z, 0); acc2(a1, v0.w, 2);
            acc2(a2, v1.x, 0); acc2(a2, v1.y, 2);
            acc2(a3, v1.z, 0); acc2(a3, v1.w, 2);
        }
        const float inv = (s1 > s0) ? 1.0f / (float)(s1 - s0) : 0.0f;
        a0 *= inv; a1 *= inv; a2 *= inv; a3 *= inv;
        p[r][0].x = pk2(a0[0], a0[1]);
        p[r][0].y = pk2(a0[2], a0[3]);
        p[r][0].z = pk2(a1[0], a1[1]);
        p[r][0].w = pk2(a1[2], a1[3]);
        p[r][1].x = pk2(a2[0], a2[1]);
        p[r][1].y = pk2(a2[2], a2[3]);
        p[r][1].z = pk2(a3[0], a3[1]);
        p[r][1].w = pk2(a3[2], a3[3]);
    }

    float4e acc[2][2];
#pragma unroll
    for (int i = 0; i < 2; i++)
#pragma unroll
        for (int j = 0; j < 2; j++)
#pragma unroll
            for (int q = 0; q < 4; q++) acc[i][j][q] = 0.0f;

    const int ck0 = sub8 * 2;
    const int wr0 = grp * 128 + ((ck0 ^ (grp & 15)) << 3);
    const int wr1 = grp * 128 + (((ck0 + 1) ^ (grp & 15)) << 3);

#pragma unroll
    for (int s = 0; s < 9; s++) {
        // ---- publish A-tile for this relation ----
        if (s < 8) {
            *(uint4*)&As[wr0] = p[s][0];
            *(uint4*)&As[wr1] = p[s][1];
        } else {
            // root/self: bf16 row copy (gather through ids for layer 1)
            uint4 r0 = {0u, 0u, 0u, 0u}, r1 = {0u, 0u, 0u, 0u};
            if (rowok) {
                int srcn = HAS_IDX ? ids[mydst] : mydst;
                const uint4* xp = (const uint4*)(x16 + (size_t)srcn * HD + sub8 * 16);
                r0 = xp[0];
                r1 = xp[1];
            }
            *(uint4*)&As[wr0] = r0;
            *(uint4*)&As[wr1] = r1;
        }
        __syncthreads();   // drains Ws(s) DMA + As ds_writes

        // ---- MFMA: A and B from LDS ----
#pragma unroll
        for (int k0 = 0; k0 < 4; k0++) {
            short8 af[2], bf[2];
            const int ck = k0 * 4 + quad;
#pragma unroll
            for (int rt = 0; rt < 2; rt++) {
                int m = rowbase + rt * 16 + ln15;
                af[rt] = *(const short8*)&As[m * 128 + ((ck ^ (m & 15)) << 3)];
            }
#pragma unroll
            for (int ct = 0; ct < 2; ct++) {
                int n = colbase + ct * 16 + ln15;
                bf[ct] = *(const short8*)&Ws[n * 128 + ((ck ^ (n & 15)) << 3)];
            }
#pragma unroll
            for (int rt = 0; rt < 2; rt++)
#pragma unroll
                for (int ct = 0; ct < 2; ct++)
                    acc[rt][ct] = __builtin_amdgcn_mfma_f32_16x16x32_bf16(
                        af[rt], bf[ct], acc[rt][ct], 0, 0, 0);
        }
        __syncthreads();   // all waves done reading As/Ws

        // ---- issue Ws(s+1) DMA (drained at next phase's first barrier) ----
        if (s < 8) {
            const unsigned short* Wsrc = WT + (s + 1) * 16384;
#pragma unroll
            for (int i = 0; i < 4; i++) {
                int c = i * 512 + tid;
                int f = c >> 4;
                int cc = c & 15;
                const void* src = (const void*)(Wsrc + f * 128 + ((cc ^ (f & 15)) << 3));
                int cbase = i * 512 + (tid & ~63);
                gload_lds16(src, (char*)Ws + (size_t)cbase * 16);
            }
        }
    }

    // ---- epilogue ----
#pragma unroll
    for (int ct = 0; ct < 2; ct++) {
        int ncol = colbase + ct * 16 + ln15;
        float bv = bias[ncol];
#pragma unroll
        for (int rt = 0; rt < 2; rt++) {
#pragma unroll
            for (int rg = 0; rg < 4; rg++) {
                int rowg = block0 + rowbase + rt * 16 + quad * 4 + rg;
                if (rowg < N) {
                    float v = acc[rt][ct][rg] + bv;
                    if (ACT == 0) {
                        v = fmaxf(v, 0.0f);
                        ((unsigned short*)CoutV)[(size_t)rowg * HD + ncol] = f2bf(v);
                    } else {
                        v = 1.0f / (1.0f + expf(-v));
                        ((float*)CoutV)[(size_t)rowg * HD + ncol] = v;
                    }
                }
            }
        }
    }
}

extern "C" void kernel_launch(void* const* d_in, const int* in_sizes, int n_in,
                              void* d_out, int out_size, void* d_ws, size_t ws_size,
                              hipStream_t stream) {
    const int*   x_ids = (const int*)d_in[0];
    const int*   ei    = (const int*)d_in[1];
    const int*   et    = (const int*)d_in[2];
    const float* emb   = (const float*)d_in[3];
    const float* W1    = (const float*)d_in[4];
    const float* root1 = (const float*)d_in[5];
    const float* b1    = (const float*)d_in[6];
    const float* W2    = (const float*)d_in[7];
    const float* root2 = (const float*)d_in[8];
    const float* b2    = (const float*)d_in[9];

    const int N = in_sizes[0];
    const int E = in_sizes[1] / 2;
    const int NS = RNUM * N;
    const long long embElems = (long long)in_sizes[3];   // NUM_ENTITIES * HD
    float* out = (float*)d_out;

    // ---- arenas (row_start has NS+1 entries, padded to 16 B) ----
    char* ws = (char*)d_ws;
    size_t off = 0;
    int* row_start = (int*)(ws + off); off += (size_t)(NS + 4) * 4;             // 3.2 MB
    int* col       = (int*)(ws + off); off += (size_t)E * 4;                    // 2.0 MB
    int* colE      = (int*)(ws + off); off += (size_t)E * 4;                    // 2.0 MB
    int* bsum      = (int*)(ws + off); off += 4096;
    unsigned short* WT    = (unsigned short*)(ws + off); off += (size_t)18 * 16384 * 2;
    unsigned short* emb16 = (unsigned short*)(ws + off); off += (size_t)embElems * 2;  // 25.6 MB
    unsigned short* z16   = (unsigned short*)(ws + off); off += (size_t)N * HD * 2;    // 25.6 MB
    int* cur = (int*)z16;   // alias: cur dead before z16 is first written

    const int scanBlocks = (NS + SCAN_BS - 1) / SCAN_BS;
    const int layerGrid = (N + 63) / 64;

    // ---- CSR build (dst-major) ----
    zero_i<<<(NS + 255) / 256, 256, 0, stream>>>(cur, NS);
    count_kernel<<<(E + 255) / 256, 256, 0, stream>>>(ei, et, cur, E, N);
    scan1<<<scanBlocks, 256, 0, stream>>>(cur, row_start, bsum, NS);
    scan2<<<1, 512, 0, stream>>>(bsum, scanBlocks);
    scan3<<<scanBlocks, 256, 0, stream>>>(row_start, cur, bsum, NS);
    fill_kernel<<<(E + 255) / 256, 256, 0, stream>>>(ei, et, x_ids, cur, col, colE,
                                                     row_start, E, N);

    // ---- weights -> bf16 transposed + emb -> bf16 (one launch) ----
    {
        long long n8 = embElems / 8;
        long long total = 18 * 16384 + n8;
        prep_kernel<<<(unsigned int)((total + 255) / 256), 256, 0, stream>>>(
            W1, root1, W2, root2, WT, emb, emb16, n8);
    }

    // ---- layer 1: z16 = bf16(relu(agg(emb16) + emb16[ids]@root1 + b1)) ----
    rgcn_fused<true, 0><<<layerGrid, 512, 0, stream>>>(
        row_start, colE, x_ids, emb16, WT, b1, (void*)z16, N, E);
    // ---- layer 2: out = sigmoid(agg(z16) + z16@root2 + b2) ----
    rgcn_fused<false, 1><<<layerGrid, 512, 0, stream>>>(
        row_start, col, nullptr, z16, WT + 9 * 16384, b2, (void*)out, N, E);
}

// Round 11
// 464.759 us; speedup vs baseline: 1.2749x; 1.0862x over previous
//
#include <hip/hip_runtime.h>

#define HD 128
#define RNUM 8
#define SCAN_BS 2048

typedef __attribute__((ext_vector_type(8))) short short8;
typedef __attribute__((ext_vector_type(4))) float float4e;

__device__ __forceinline__ unsigned short f2bf(float f) {
    unsigned int u = __float_as_uint(f);
    u += 0x7fffu + ((u >> 16) & 1u);   // RNE
    return (unsigned short)(u >> 16);
}

__device__ __forceinline__ unsigned int pk2(float lo, float hi) {
    return (unsigned int)f2bf(lo) | ((unsigned int)f2bf(hi) << 16);
}

// accumulate 2 bf16 packed in u into a[i], a[i+1]
__device__ __forceinline__ void acc2(float4e& a, unsigned int u, int i) {
    a[i]     += __uint_as_float(u << 16);
    a[i + 1] += __uint_as_float(u & 0xffff0000u);
}

__device__ __forceinline__ void gload_lds16(const void* g, void* l) {
    __builtin_amdgcn_global_load_lds(
        (const __attribute__((address_space(1))) void*)g,
        (__attribute__((address_space(3))) void*)l, 16, 0, 0);
}

// ---------------- small kernels ----------------
__global__ void zero_i(int* __restrict__ p, int n) {
    int g = blockIdx.x * blockDim.x + threadIdx.x;
    if (g < n) p[g] = 0;
}

// weights -> bf16 transposed WT[mat][f][d], plus emb -> bf16, one launch
__global__ void prep_kernel(const float* __restrict__ W1, const float* __restrict__ r1,
                            const float* __restrict__ W2, const float* __restrict__ r2,
                            unsigned short* __restrict__ WT,
                            const float* __restrict__ emb, unsigned short* __restrict__ emb16,
                            long long n8) {
    long long g = (long long)blockIdx.x * blockDim.x + threadIdx.x;
    if (g < 18 * 16384) {
        int gi = (int)g;
        int mat = gi >> 14;
        int idx = gi & 16383;
        int d = idx >> 7;
        int f = idx & 127;
        const float* src;
        int m;
        if (mat < 8)       { src = W1; m = mat; }
        else if (mat == 8) { src = r1; m = 0; }
        else if (mat < 17) { src = W2; m = mat - 9; }
        else               { src = r2; m = 0; }
        WT[mat * 16384 + f * 128 + d] = f2bf(src[(size_t)m * 16384 + d * 128 + f]);
    }
    long long h = g - 18 * 16384;
    if (h >= 0 && h < n8) {
        const float4* p = (const float4*)(emb + h * 8);
        float4 v0 = p[0], v1 = p[1];
        uint4 o;
        o.x = pk2(v0.x, v0.y);
        o.y = pk2(v0.z, v0.w);
        o.z = pk2(v1.x, v1.y);
        o.w = pk2(v1.z, v1.w);
        *(uint4*)(emb16 + h * 8) = o;
    }
}

// ---------------- CSR build (dst-major: seg = dst*8 + r) ----------------
__global__ void count_kernel(const int* __restrict__ ei, const int* __restrict__ et,
                             int* __restrict__ cnt, int E, int N) {
    int e = blockIdx.x * blockDim.x + threadIdx.x;
    if (e < E) atomicAdd(&cnt[ei[E + e] * RNUM + et[e]], 1);
}

__global__ void scan1(const int* __restrict__ in, int* __restrict__ out,
                      int* __restrict__ bsum, int n) {
    __shared__ int s[256];
    const int tid = threadIdx.x;
    const int base = blockIdx.x * SCAN_BS + tid * 8;
    int v[8];
    int sum = 0;
#pragma unroll
    for (int j = 0; j < 8; j++) {
        int x = (base + j < n) ? in[base + j] : 0;
        v[j] = sum;
        sum += x;
    }
    s[tid] = sum;
    __syncthreads();
    for (int off = 1; off < 256; off <<= 1) {
        int tv = (tid >= off) ? s[tid - off] : 0;
        __syncthreads();
        if (tid >= off) s[tid] += tv;
        __syncthreads();
    }
    int excl = (tid > 0) ? s[tid - 1] : 0;
    if (tid == 255) bsum[blockIdx.x] = s[255];
#pragma unroll
    for (int j = 0; j < 8; j++)
        if (base + j < n) out[base + j] = v[j] + excl;
}

__global__ void scan2(int* __restrict__ bsum, int nb) {
    __shared__ int s[512];
    const int tid = threadIdx.x;
    s[tid] = (tid < nb) ? bsum[tid] : 0;
    __syncthreads();
    for (int off = 1; off < 512; off <<= 1) {
        int tv = (tid >= off) ? s[tid - off] : 0;
        __syncthreads();
        if (tid >= off) s[tid] += tv;
        __syncthreads();
    }
    if (tid < nb) bsum[tid] = (tid > 0) ? s[tid - 1] : 0;
}

__global__ void scan3(int* __restrict__ out, int* __restrict__ cur,
                      const int* __restrict__ bsum, int n) {
    const int base = blockIdx.x * SCAN_BS + threadIdx.x * 8;
    const int add = bsum[blockIdx.x];
#pragma unroll
    for (int j = 0; j < 8; j++) {
        int i = base + j;
        if (i < n) {
            int v = out[i] + add;
            out[i] = v;
            cur[i] = v;
        }
    }
}

// fill: col = src node id (layer 2), colE = pre-resolved entity id (layer 1).
// Thread 0 also writes the terminating boundary row_start[8*N] = E.
__global__ void fill_kernel(const int* __restrict__ ei, const int* __restrict__ et,
                            const int* __restrict__ ids,
                            int* __restrict__ cur, int* __restrict__ col,
                            int* __restrict__ colE, int* __restrict__ row_start,
                            int E, int N) {
    int e = blockIdx.x * blockDim.x + threadIdx.x;
    if (e == 0) row_start[RNUM * N] = E;
    if (e < E) {
        int src = ei[e];
        int pos = atomicAdd(&cur[ei[E + e] * RNUM + et[e]], 1);
        col[pos] = src;
        colE[pos] = ids[src];
    }
}

// ---------------- fused layer: register-walk (named regs, spill-proof) ----------------
// 512 threads = 8 waves, 32-row tile. As 8 KB + Ws 32 KB = 40 KB.
// Walk ALL 8 relations first into NAMED uint4 registers p0..p7 (one 16-lane group
// per row, 16 B/lane; segments contiguous in dst-major CSR; walk-max paid ONCE),
// then 9 uniform phases {publish -> barrier -> MFMA -> barrier -> DMA Ws(s+1)}.
template <bool HAS_IDX, int ACT>   // ACT: 0 = relu -> bf16 out, 1 = sigmoid -> f32 out
__launch_bounds__(512, 4)
__global__ void rgcn_fused(const int* __restrict__ row_start, const int* __restrict__ col,
                           const int* __restrict__ ids,
                           const unsigned short* __restrict__ x16,
                           const unsigned short* __restrict__ WT,
                           const float* __restrict__ bias,
                           void* __restrict__ CoutV, int N, int E) {
    __shared__ unsigned short As[32 * 128];    // 8 KB
    __shared__ unsigned short Ws[128 * 128];   // 32 KB

    const int tid = threadIdx.x;
    const int block0 = blockIdx.x * 32;
    // MFMA mapping (8 waves: 2 row strips of 16 x 4 col strips of 32)
    const int w = tid >> 6;
    const int lane = tid & 63;
    const int ln15 = lane & 15;
    const int quad = lane >> 4;
    const int rowbase = (w & 1) * 16;
    const int colbase = (w >> 1) * 32;
    // walk mapping: 32 groups of 16 lanes; group g owns row g (16 B per lane)
    const int grp = tid >> 4;
    const int sub16 = tid & 15;
    const int mydst = block0 + grp;
    const bool rowok = (mydst < N);

    // ---- stage Ws(0): async DMA, in flight across the walk ----
    {
        const unsigned short* Wsrc = WT;
#pragma unroll
        for (int i = 0; i < 4; i++) {
            int c = i * 512 + tid;
            int f = c >> 4;
            int cc = c & 15;
            const void* src = (const void*)(Wsrc + f * 128 + ((cc ^ (f & 15)) << 3));
            int cbase = i * 512 + (tid & ~63);   // wave-uniform base, +lane*16
            gload_lds16(src, (char*)Ws + (size_t)cbase * 16);
        }
    }

    // ---- walk all 8 relations into NAMED registers (no indexable array) ----
    uint4 p0, p1, p2, p3, p4, p5, p6, p7;
#define WALK(R, P)                                                                  \
    {                                                                               \
        float4e a0 = {0.f, 0.f, 0.f, 0.f};                                          \
        float4e a1 = {0.f, 0.f, 0.f, 0.f};                                          \
        int s0 = 0, s1 = 0;                                                         \
        if (rowok) {                                                                \
            s0 = row_start[mydst * 8 + R];                                          \
            s1 = row_start[mydst * 8 + R + 1];                                      \
        }                                                                           \
        _Pragma("unroll 1")                                                         \
        for (int e = s0; e < s1; e++) {                                             \
            int c = col[e];                                                         \
            uint4 v = *(const uint4*)(x16 + (size_t)c * HD + sub16 * 8);            \
            acc2(a0, v.x, 0); acc2(a0, v.y, 2);                                     \
            acc2(a1, v.z, 0); acc2(a1, v.w, 2);                                     \
        }                                                                           \
        const float inv = (s1 > s0) ? 1.0f / (float)(s1 - s0) : 0.0f;               \
        a0 *= inv; a1 *= inv;                                                       \
        P.x = pk2(a0[0], a0[1]); P.y = pk2(a0[2], a0[3]);                           \
        P.z = pk2(a1[0], a1[1]); P.w = pk2(a1[2], a1[3]);                           \
    }
    WALK(0, p0) WALK(1, p1) WALK(2, p2) WALK(3, p3)
    WALK(4, p4) WALK(5, p5) WALK(6, p6) WALK(7, p7)
#undef WALK

    float4e acc0 = {0.f, 0.f, 0.f, 0.f};
    float4e acc1 = {0.f, 0.f, 0.f, 0.f};

    const int wr = grp * 128 + ((sub16 ^ (grp & 15)) << 3);
    const int m0 = rowbase + ln15;
    const int n0 = colbase + ln15;
    const int n1 = colbase + 16 + ln15;

#define MFMA_PHASE()                                                                \
    {                                                                               \
        __syncthreads();                                                            \
        _Pragma("unroll")                                                           \
        for (int k0 = 0; k0 < 4; k0++) {                                            \
            const int ck = k0 * 4 + quad;                                           \
            short8 af = *(const short8*)&As[m0 * 128 + ((ck ^ (m0 & 15)) << 3)];    \
            short8 bf0 = *(const short8*)&Ws[n0 * 128 + ((ck ^ (n0 & 15)) << 3)];   \
            short8 bf1 = *(const short8*)&Ws[n1 * 128 + ((ck ^ (n1 & 15)) << 3)];   \
            acc0 = __builtin_amdgcn_mfma_f32_16x16x32_bf16(af, bf0, acc0, 0, 0, 0); \
            acc1 = __builtin_amdgcn_mfma_f32_16x16x32_bf16(af, bf1, acc1, 0, 0, 0); \
        }                                                                           \
        __syncthreads();                                                            \
    }

#define PHASE(S, P)                                                                 \
    {                                                                               \
        *(uint4*)&As[wr] = P;                                                       \
        MFMA_PHASE();                                                               \
        const unsigned short* Wsrc = WT + (S + 1) * 16384;                          \
        _Pragma("unroll")                                                           \
        for (int i = 0; i < 4; i++) {                                               \
            int c = i * 512 + tid;                                                  \
            int f = c >> 4;                                                         \
            int cc = c & 15;                                                        \
            const void* src = (const void*)(Wsrc + f * 128 + ((cc ^ (f & 15)) << 3)); \
            int cbase = i * 512 + (tid & ~63);                                      \
            gload_lds16(src, (char*)Ws + (size_t)cbase * 16);                       \
        }                                                                           \
    }

    PHASE(0, p0) PHASE(1, p1) PHASE(2, p2) PHASE(3, p3)
    PHASE(4, p4) PHASE(5, p5) PHASE(6, p6) PHASE(7, p7)
#undef PHASE

    // ---- root/self phase (s == 8): Ws(8) already staged by PHASE(7) ----
    {
        uint4 r0 = {0u, 0u, 0u, 0u};
        if (rowok) {
            int srcn = HAS_IDX ? ids[mydst] : mydst;
            r0 = *(const uint4*)(x16 + (size_t)srcn * HD + sub16 * 8);
        }
        *(uint4*)&As[wr] = r0;
        MFMA_PHASE();
    }
#undef MFMA_PHASE

    // ---- epilogue: acc0 -> cols [colbase, +16), acc1 -> cols [colbase+16, +16) ----
#pragma unroll
    for (int rg = 0; rg < 4; rg++) {
        int rowg = block0 + rowbase + quad * 4 + rg;
        if (rowg < N) {
            {
                int ncol = colbase + ln15;
                float v = acc0[rg] + bias[ncol];
                if (ACT == 0) {
                    v = fmaxf(v, 0.0f);
                    ((unsigned short*)CoutV)[(size_t)rowg * HD + ncol] = f2bf(v);
                } else {
                    v = 1.0f / (1.0f + expf(-v));
                    ((float*)CoutV)[(size_t)rowg * HD + ncol] = v;
                }
            }
            {
                int ncol = colbase + 16 + ln15;
                float v = acc1[rg] + bias[ncol];
                if (ACT == 0) {
                    v = fmaxf(v, 0.0f);
                    ((unsigned short*)CoutV)[(size_t)rowg * HD + ncol] = f2bf(v);
                } else {
                    v = 1.0f / (1.0f + expf(-v));
                    ((float*)CoutV)[(size_t)rowg * HD + ncol] = v;
                }
            }
        }
    }
}

extern "C" void kernel_launch(void* const* d_in, const int* in_sizes, int n_in,
                              void* d_out, int out_size, void* d_ws, size_t ws_size,
                              hipStream_t stream) {
    const int*   x_ids = (const int*)d_in[0];
    const int*   ei    = (const int*)d_in[1];
    const int*   et    = (const int*)d_in[2];
    const float* emb   = (const float*)d_in[3];
    const float* W1    = (const float*)d_in[4];
    const float* root1 = (const float*)d_in[5];
    const float* b1    = (const float*)d_in[6];
    const float* W2    = (const float*)d_in[7];
    const float* root2 = (const float*)d_in[8];
    const float* b2    = (const float*)d_in[9];

    const int N = in_sizes[0];
    const int E = in_sizes[1] / 2;
    const int NS = RNUM * N;
    const long long embElems = (long long)in_sizes[3];   // NUM_ENTITIES * HD
    float* out = (float*)d_out;

    // ---- arenas (row_start has NS+1 entries, padded to 16 B) ----
    char* ws = (char*)d_ws;
    size_t off = 0;
    int* row_start = (int*)(ws + off); off += (size_t)(NS + 4) * 4;             // 3.2 MB
    int* col       = (int*)(ws + off); off += (size_t)E * 4;                    // 2.0 MB
    int* colE      = (int*)(ws + off); off += (size_t)E * 4;                    // 2.0 MB
    int* bsum      = (int*)(ws + off); off += 4096;
    unsigned short* WT    = (unsigned short*)(ws + off); off += (size_t)18 * 16384 * 2;
    unsigned short* emb16 = (unsigned short*)(ws + off); off += (size_t)embElems * 2;  // 25.6 MB
    unsigned short* z16   = (unsigned short*)(ws + off); off += (size_t)N * HD * 2;    // 25.6 MB
    int* cur = (int*)z16;   // alias: cur dead before z16 is first written

    const int scanBlocks = (NS + SCAN_BS - 1) / SCAN_BS;
    const int layerGrid = (N + 31) / 32;

    // ---- CSR build (dst-major) ----
    zero_i<<<(NS + 255) / 256, 256, 0, stream>>>(cur, NS);
    count_kernel<<<(E + 255) / 256, 256, 0, stream>>>(ei, et, cur, E, N);
    scan1<<<scanBlocks, 256, 0, stream>>>(cur, row_start, bsum, NS);
    scan2<<<1, 512, 0, stream>>>(bsum, scanBlocks);
    scan3<<<scanBlocks, 256, 0, stream>>>(row_start, cur, bsum, NS);
    fill_kernel<<<(E + 255) / 256, 256, 0, stream>>>(ei, et, x_ids, cur, col, colE,
                                                     row_start, E, N);

    // ---- weights -> bf16 transposed + emb -> bf16 (one launch) ----
    {
        long long n8 = embElems / 8;
        long long total = 18 * 16384 + n8;
        prep_kernel<<<(unsigned int)((total + 255) / 256), 256, 0, stream>>>(
            W1, root1, W2, root2, WT, emb, emb16, n8);
    }

    // ---- layer 1: z16 = bf16(relu(agg(emb16) + emb16[ids]@root1 + b1)) ----
    rgcn_fused<true, 0><<<layerGrid, 512, 0, stream>>>(
        row_start, colE, x_ids, emb16, WT, b1, (void*)z16, N, E);
    // ---- layer 2: out = sigmoid(agg(z16) + z16@root2 + b2) ----
    rgcn_fused<false, 1><<<layerGrid, 512, 0, stream>>>(
        row_start, col, nullptr, z16, WT + 9 * 16384, b2, (void*)out, N, E);
}

// Round 12
// 409.138 us; speedup vs baseline: 1.4482x; 1.1359x over previous
//
#include <hip/hip_runtime.h>

#define HD 128
#define RNUM 8
#define SCAN_BS 2048

typedef __attribute__((ext_vector_type(8))) short short8;
typedef __attribute__((ext_vector_type(4))) float float4e;

__device__ __forceinline__ unsigned short f2bf(float f) {
    unsigned int u = __float_as_uint(f);
    u += 0x7fffu + ((u >> 16) & 1u);   // RNE
    return (unsigned short)(u >> 16);
}

__device__ __forceinline__ unsigned int pk2(float lo, float hi) {
    return (unsigned int)f2bf(lo) | ((unsigned int)f2bf(hi) << 16);
}

// accumulate 2 bf16 packed in u into a[i], a[i+1]
__device__ __forceinline__ void acc2(float4e& a, unsigned int u, int i) {
    a[i]     += __uint_as_float(u << 16);
    a[i + 1] += __uint_as_float(u & 0xffff0000u);
}

__device__ __forceinline__ void gload_lds16(const void* g, void* l) {
    __builtin_amdgcn_global_load_lds(
        (const __attribute__((address_space(1))) void*)g,
        (__attribute__((address_space(3))) void*)l, 16, 0, 0);
}

// ---------------- small kernels ----------------
__global__ void zero_i(int* __restrict__ p, int n) {
    int g = blockIdx.x * blockDim.x + threadIdx.x;
    if (g < n) p[g] = 0;
}

// weights -> bf16 transposed WT[mat][f][d], plus emb -> bf16, one launch
__global__ void prep_kernel(const float* __restrict__ W1, const float* __restrict__ r1,
                            const float* __restrict__ W2, const float* __restrict__ r2,
                            unsigned short* __restrict__ WT,
                            const float* __restrict__ emb, unsigned short* __restrict__ emb16,
                            long long n8) {
    long long g = (long long)blockIdx.x * blockDim.x + threadIdx.x;
    if (g < 18 * 16384) {
        int gi = (int)g;
        int mat = gi >> 14;
        int idx = gi & 16383;
        int d = idx >> 7;
        int f = idx & 127;
        const float* src;
        int m;
        if (mat < 8)       { src = W1; m = mat; }
        else if (mat == 8) { src = r1; m = 0; }
        else if (mat < 17) { src = W2; m = mat - 9; }
        else               { src = r2; m = 0; }
        WT[mat * 16384 + f * 128 + d] = f2bf(src[(size_t)m * 16384 + d * 128 + f]);
    }
    long long h = g - 18 * 16384;
    if (h >= 0 && h < n8) {
        const float4* p = (const float4*)(emb + h * 8);
        float4 v0 = p[0], v1 = p[1];
        uint4 o;
        o.x = pk2(v0.x, v0.y);
        o.y = pk2(v0.z, v0.w);
        o.z = pk2(v1.x, v1.y);
        o.w = pk2(v1.z, v1.w);
        *(uint4*)(emb16 + h * 8) = o;
    }
}

// ---------------- CSR build (dst-major: seg = dst*8 + r) ----------------
__global__ void count_kernel(const int* __restrict__ ei, const int* __restrict__ et,
                             int* __restrict__ cnt, int E, int N) {
    int e = blockIdx.x * blockDim.x + threadIdx.x;
    if (e < E) atomicAdd(&cnt[ei[E + e] * RNUM + et[e]], 1);
}

__global__ void scan1(const int* __restrict__ in, int* __restrict__ out,
                      int* __restrict__ bsum, int n) {
    __shared__ int s[256];
    const int tid = threadIdx.x;
    const int base = blockIdx.x * SCAN_BS + tid * 8;
    int v[8];
    int sum = 0;
#pragma unroll
    for (int j = 0; j < 8; j++) {
        int x = (base + j < n) ? in[base + j] : 0;
        v[j] = sum;
        sum += x;
    }
    s[tid] = sum;
    __syncthreads();
    for (int off = 1; off < 256; off <<= 1) {
        int tv = (tid >= off) ? s[tid - off] : 0;
        __syncthreads();
        if (tid >= off) s[tid] += tv;
        __syncthreads();
    }
    int excl = (tid > 0) ? s[tid - 1] : 0;
    if (tid == 255) bsum[blockIdx.x] = s[255];
#pragma unroll
    for (int j = 0; j < 8; j++)
        if (base + j < n) out[base + j] = v[j] + excl;
}

__global__ void scan2(int* __restrict__ bsum, int nb) {
    __shared__ int s[512];
    const int tid = threadIdx.x;
    s[tid] = (tid < nb) ? bsum[tid] : 0;
    __syncthreads();
    for (int off = 1; off < 512; off <<= 1) {
        int tv = (tid >= off) ? s[tid - off] : 0;
        __syncthreads();
        if (tid >= off) s[tid] += tv;
        __syncthreads();
    }
    if (tid < nb) bsum[tid] = (tid > 0) ? s[tid - 1] : 0;
}

__global__ void scan3(int* __restrict__ out, int* __restrict__ cur,
                      const int* __restrict__ bsum, int n) {
    const int base = blockIdx.x * SCAN_BS + threadIdx.x * 8;
    const int add = bsum[blockIdx.x];
#pragma unroll
    for (int j = 0; j < 8; j++) {
        int i = base + j;
        if (i < n) {
            int v = out[i] + add;
            out[i] = v;
            cur[i] = v;
        }
    }
}

// fill: col = src node id (layer 2), colE = pre-resolved entity id (layer 1).
// Thread 0 also writes the terminating boundary row_start[8*N] = E.
__global__ void fill_kernel(const int* __restrict__ ei, const int* __restrict__ et,
                            const int* __restrict__ ids,
                            int* __restrict__ cur, int* __restrict__ col,
                            int* __restrict__ colE, int* __restrict__ row_start,
                            int E, int N) {
    int e = blockIdx.x * blockDim.x + threadIdx.x;
    if (e == 0) row_start[RNUM * N] = E;
    if (e < E) {
        int src = ei[e];
        int pos = atomicAdd(&cur[ei[E + e] * RNUM + et[e]], 1);
        col[pos] = src;
        colE[pos] = ids[src];
    }
}

// ---------------- fused layer: 512 threads, 128-row tile ----------------
// R4 geometry (2 blocks/CU, 2x phase-overhead amortization vs 64-row tile)
// + R8 data path (bf16 gathers, dst-major one-line boundaries, 4-lane walk).
// Per relation s: DMA Ws(s) (hidden under walk), 4-lane groups walk the
// contiguous dst-major segment (128 rows in flight/block), barrier, MFMA, barrier.
template <bool HAS_IDX, int ACT>   // ACT: 0 = relu -> bf16 out, 1 = sigmoid -> f32 out
__launch_bounds__(512, 4)
__global__ void rgcn_fused(const int* __restrict__ row_start, const int* __restrict__ col,
                           const int* __restrict__ ids,
                           const unsigned short* __restrict__ x16,
                           const unsigned short* __restrict__ WT,
                           const float* __restrict__ bias,
                           void* __restrict__ CoutV, int N, int E) {
    __shared__ unsigned short As[128 * 128];   // 32 KB
    __shared__ unsigned short Ws[128 * 128];   // 32 KB

    const int tid = threadIdx.x;
    const int block0 = blockIdx.x * 128;
    // MFMA mapping (8 waves: 2 row strips of 64 x 4 col strips of 32) — R4-verified
    const int w = tid >> 6;
    const int lane = tid & 63;
    const int ln15 = lane & 15;
    const int quad = lane >> 4;
    const int rowbase = (w & 1) * 64;
    const int colbase = (w >> 1) * 32;
    // walk mapping: 128 groups of 4 lanes; group g owns row g (64 B per lane)
    const int grp = tid >> 2;
    const int sub4 = tid & 3;
    const int mydst = block0 + grp;
    const bool rowok = (mydst < N);

    float4e acc[4][2];
#pragma unroll
    for (int i = 0; i < 4; i++)
#pragma unroll
        for (int j = 0; j < 2; j++)
#pragma unroll
            for (int q = 0; q < 4; q++) acc[i][j][q] = 0.0f;

#pragma unroll 1
    for (int s = 0; s < RNUM; s++) {
        // ---- stage Ws(s): async DMA; latency hides under the walk below ----
        {
            const unsigned short* Wsrc = WT + s * 16384;
#pragma unroll
            for (int i = 0; i < 4; i++) {
                int c = i * 512 + tid;
                int f = c >> 4;
                int cc = c & 15;
                const void* src = (const void*)(Wsrc + f * 128 + ((cc ^ (f & 15)) << 3));
                int cbase = i * 512 + (tid & ~63);   // wave-uniform base, +lane*16
                gload_lds16(src, (char*)Ws + (size_t)cbase * 16);
            }
        }
        // ---- stage A tile: mean-aggregate; boundaries L1-hot (one line per row) ----
        {
            float4e a[8];
#pragma unroll
            for (int j = 0; j < 8; j++) a[j] = (float4e){0.f, 0.f, 0.f, 0.f};
            int s0 = 0, s1 = 0;
            if (rowok) {
                s0 = row_start[mydst * 8 + s];
                s1 = row_start[mydst * 8 + s + 1];
            }
            const float inv = (s1 > s0) ? 1.0f / (float)(s1 - s0) : 0.0f;
#pragma unroll 1
            for (int e = s0; e < s1; e++) {
                int c = col[e];
                const uint4* xp = (const uint4*)(x16 + (size_t)c * HD + sub4 * 32);
                uint4 v0 = xp[0], v1 = xp[1], v2 = xp[2], v3 = xp[3];
                acc2(a[0], v0.x, 0); acc2(a[0], v0.y, 2);
                acc2(a[1], v0.z, 0); acc2(a[1], v0.w, 2);
                acc2(a[2], v1.x, 0); acc2(a[2], v1.y, 2);
                acc2(a[3], v1.z, 0); acc2(a[3], v1.w, 2);
                acc2(a[4], v2.x, 0); acc2(a[4], v2.y, 2);
                acc2(a[5], v2.z, 0); acc2(a[5], v2.w, 2);
                acc2(a[6], v3.x, 0); acc2(a[6], v3.y, 2);
                acc2(a[7], v3.z, 0); acc2(a[7], v3.w, 2);
            }
#pragma unroll
            for (int j = 0; j < 8; j++) a[j] *= inv;
#pragma unroll
            for (int j = 0; j < 4; j++) {
                uint4 o;
                o.x = pk2(a[2 * j][0], a[2 * j][1]);
                o.y = pk2(a[2 * j][2], a[2 * j][3]);
                o.z = pk2(a[2 * j + 1][0], a[2 * j + 1][1]);
                o.w = pk2(a[2 * j + 1][2], a[2 * j + 1][3]);
                int ck = sub4 * 4 + j;
                *(uint4*)&As[grp * 128 + ((ck ^ (grp & 15)) << 3)] = o;
            }
        }
        __syncthreads();

        // ---- MFMA: A and B from LDS ----
#pragma unroll
        for (int k0 = 0; k0 < 4; k0++) {
            short8 af[4], bf[2];
            const int ck = k0 * 4 + quad;
#pragma unroll
            for (int rt = 0; rt < 4; rt++) {
                int m = rowbase + rt * 16 + ln15;
                af[rt] = *(const short8*)&As[m * 128 + ((ck ^ (m & 15)) << 3)];
            }
#pragma unroll
            for (int ct = 0; ct < 2; ct++) {
                int n = colbase + ct * 16 + ln15;
                bf[ct] = *(const short8*)&Ws[n * 128 + ((ck ^ (n & 15)) << 3)];
            }
#pragma unroll
            for (int rt = 0; rt < 4; rt++)
#pragma unroll
                for (int ct = 0; ct < 2; ct++)
                    acc[rt][ct] = __builtin_amdgcn_mfma_f32_16x16x32_bf16(
                        af[rt], bf[ct], acc[rt][ct], 0, 0, 0);
        }
        __syncthreads();
    }

    // ---- root/self phase (s == 8) ----
    {
        const unsigned short* Wsrc = WT + RNUM * 16384;
#pragma unroll
        for (int i = 0; i < 4; i++) {
            int c = i * 512 + tid;
            int f = c >> 4;
            int cc = c & 15;
            const void* src = (const void*)(Wsrc + f * 128 + ((cc ^ (f & 15)) << 3));
            int cbase = i * 512 + (tid & ~63);
            gload_lds16(src, (char*)Ws + (size_t)cbase * 16);
        }
        uint4 o0 = {0u, 0u, 0u, 0u}, o1 = o0, o2 = o0, o3 = o0;
        if (rowok) {
            int srcn = HAS_IDX ? ids[mydst] : mydst;
            const uint4* xp = (const uint4*)(x16 + (size_t)srcn * HD + sub4 * 32);
            o0 = xp[0]; o1 = xp[1]; o2 = xp[2]; o3 = xp[3];
        }
        const int ck0 = sub4 * 4;
        *(uint4*)&As[grp * 128 + (((ck0 + 0) ^ (grp & 15)) << 3)] = o0;
        *(uint4*)&As[grp * 128 + (((ck0 + 1) ^ (grp & 15)) << 3)] = o1;
        *(uint4*)&As[grp * 128 + (((ck0 + 2) ^ (grp & 15)) << 3)] = o2;
        *(uint4*)&As[grp * 128 + (((ck0 + 3) ^ (grp & 15)) << 3)] = o3;
        __syncthreads();
#pragma unroll
        for (int k0 = 0; k0 < 4; k0++) {
            short8 af[4], bf[2];
            const int ck = k0 * 4 + quad;
#pragma unroll
            for (int rt = 0; rt < 4; rt++) {
                int m = rowbase + rt * 16 + ln15;
                af[rt] = *(const short8*)&As[m * 128 + ((ck ^ (m & 15)) << 3)];
            }
#pragma unroll
            for (int ct = 0; ct < 2; ct++) {
                int n = colbase + ct * 16 + ln15;
                bf[ct] = *(const short8*)&Ws[n * 128 + ((ck ^ (n & 15)) << 3)];
            }
#pragma unroll
            for (int rt = 0; rt < 4; rt++)
#pragma unroll
                for (int ct = 0; ct < 2; ct++)
                    acc[rt][ct] = __builtin_amdgcn_mfma_f32_16x16x32_bf16(
                        af[rt], bf[ct], acc[rt][ct], 0, 0, 0);
        }
        __syncthreads();
    }

    // ---- epilogue ----
#pragma unroll
    for (int ct = 0; ct < 2; ct++) {
        int ncol = colbase + ct * 16 + ln15;
        float bv = bias[ncol];
#pragma unroll
        for (int rt = 0; rt < 4; rt++) {
#pragma unroll
            for (int rg = 0; rg < 4; rg++) {
                int rowg = block0 + rowbase + rt * 16 + quad * 4 + rg;
                if (rowg < N) {
                    float v = acc[rt][ct][rg] + bv;
                    if (ACT == 0) {
                        v = fmaxf(v, 0.0f);
                        ((unsigned short*)CoutV)[(size_t)rowg * HD + ncol] = f2bf(v);
                    } else {
                        v = 1.0f / (1.0f + expf(-v));
                        ((float*)CoutV)[(size_t)rowg * HD + ncol] = v;
                    }
                }
            }
        }
    }
}

extern "C" void kernel_launch(void* const* d_in, const int* in_sizes, int n_in,
                              void* d_out, int out_size, void* d_ws, size_t ws_size,
                              hipStream_t stream) {
    const int*   x_ids = (const int*)d_in[0];
    const int*   ei    = (const int*)d_in[1];
    const int*   et    = (const int*)d_in[2];
    const float* emb   = (const float*)d_in[3];
    const float* W1    = (const float*)d_in[4];
    const float* root1 = (const float*)d_in[5];
    const float* b1    = (const float*)d_in[6];
    const float* W2    = (const float*)d_in[7];
    const float* root2 = (const float*)d_in[8];
    const float* b2    = (const float*)d_in[9];

    const int N = in_sizes[0];
    const int E = in_sizes[1] / 2;
    const int NS = RNUM * N;
    const long long embElems = (long long)in_sizes[3];   // NUM_ENTITIES * HD
    float* out = (float*)d_out;

    // ---- arenas (row_start has NS+1 entries, padded to 16 B) ----
    char* ws = (char*)d_ws;
    size_t off = 0;
    int* row_start = (int*)(ws + off); off += (size_t)(NS + 4) * 4;             // 3.2 MB
    int* col       = (int*)(ws + off); off += (size_t)E * 4;                    // 2.0 MB
    int* colE      = (int*)(ws + off); off += (size_t)E * 4;                    // 2.0 MB
    int* bsum      = (int*)(ws + off); off += 4096;
    unsigned short* WT    = (unsigned short*)(ws + off); off += (size_t)18 * 16384 * 2;
    unsigned short* emb16 = (unsigned short*)(ws + off); off += (size_t)embElems * 2;  // 25.6 MB
    unsigned short* z16   = (unsigned short*)(ws + off); off += (size_t)N * HD * 2;    // 25.6 MB
    int* cur = (int*)z16;   // alias: cur dead before z16 is first written

    const int scanBlocks = (NS + SCAN_BS - 1) / SCAN_BS;
    const int layerGrid = (N + 127) / 128;

    // ---- CSR build (dst-major) ----
    zero_i<<<(NS + 255) / 256, 256, 0, stream>>>(cur, NS);
    count_kernel<<<(E + 255) / 256, 256, 0, stream>>>(ei, et, cur, E, N);
    scan1<<<scanBlocks, 256, 0, stream>>>(cur, row_start, bsum, NS);
    scan2<<<1, 512, 0, stream>>>(bsum, scanBlocks);
    scan3<<<scanBlocks, 256, 0, stream>>>(row_start, cur, bsum, NS);
    fill_kernel<<<(E + 255) / 256, 256, 0, stream>>>(ei, et, x_ids, cur, col, colE,
                                                     row_start, E, N);

    // ---- weights -> bf16 transposed + emb -> bf16 (one launch) ----
    {
        long long n8 = embElems / 8;
        long long total = 18 * 16384 + n8;
        prep_kernel<<<(unsigned int)((total + 255) / 256), 256, 0, stream>>>(
            W1, root1, W2, root2, WT, emb, emb16, n8);
    }

    // ---- layer 1: z16 = bf16(relu(agg(emb16) + emb16[ids]@root1 + b1)) ----
    rgcn_fused<true, 0><<<layerGrid, 512, 0, stream>>>(
        row_start, colE, x_ids, emb16, WT, b1, (void*)z16, N, E);
    // ---- layer 2: out = sigmoid(agg(z16) + z16@root2 + b2) ----
    rgcn_fused<false, 1><<<layerGrid, 512, 0, stream>>>(
        row_start, col, nullptr, z16, WT + 9 * 16384, b2, (void*)out, N, E);
}